// Round 7
// baseline (268.555 us; speedup 1.0000x reference)
//
#include <hip/hip_runtime.h>
#include <hip/hip_bf16.h>

#define D_MODEL 128
#define SEQ_L   4096
#define BATCH   128
#define NSEG    8     // kmean segments

typedef float f4 __attribute__((ext_vector_type(4)));
typedef float f32x4 __attribute__((ext_vector_type(4)));
typedef short bf16x8 __attribute__((ext_vector_type(8)));
typedef unsigned int u32x4 __attribute__((ext_vector_type(4)));

__device__ __forceinline__ unsigned short f2bf(float f) {
    union { float f; unsigned u; } v; v.f = f;
    unsigned r = v.u + 0x7FFFu + ((v.u >> 16) & 1u);
    return (unsigned short)(r >> 16);
}

__device__ __forceinline__ unsigned pack2bf(float lo, float hi) {
    return (unsigned)f2bf(lo) | ((unsigned)f2bf(hi) << 16);
}

// unpack 8 bf16 (u32x4) -> two f4
__device__ __forceinline__ void unpk(u32x4 v, f4& a, f4& b) {
    a[0] = __uint_as_float(v.x << 16);
    a[1] = __uint_as_float(v.x & 0xFFFF0000u);
    a[2] = __uint_as_float(v.y << 16);
    a[3] = __uint_as_float(v.y & 0xFFFF0000u);
    b[0] = __uint_as_float(v.z << 16);
    b[1] = __uint_as_float(v.z & 0xFFFF0000u);
    b[2] = __uint_as_float(v.w << 16);
    b[3] = __uint_as_float(v.w & 0xFFFF0000u);
}

// ============================ PATH A (fast, needs ~129 MB ws) ============================

// kernel 1A: partial mean over L + write bf16 copy of x + folded Wc cvt.
// grid (NSEG+1, 128), 512 threads.
__global__ __launch_bounds__(512) void kmean_a(const float* __restrict__ x,
                                               float* __restrict__ part,
                                               const float* __restrict__ Wc,
                                               unsigned short* __restrict__ wcb,
                                               unsigned short* __restrict__ xbf) {
    if (blockIdx.x == NSEG) {
        if (blockIdx.y < 8) {
            int i = blockIdx.y * 512 + threadIdx.x;   // 4096 threads x 4 floats = 16384
            f4 v = reinterpret_cast<const f4*>(Wc)[i];
            ushort4 o;
            o.x = f2bf(v[0]); o.y = f2bf(v[1]); o.z = f2bf(v[2]); o.w = f2bf(v[3]);
            reinterpret_cast<ushort4*>(wcb)[i] = o;
        }
        return;
    }
    int seg = blockIdx.x, b = blockIdx.y;
    int t = threadIdx.x;
    int c4 = t & 31, ph = t >> 5;                 // ph: 0..15
    const f4* xb = reinterpret_cast<const f4*>(x + (size_t)b * SEQ_L * D_MODEL);
    unsigned short* xbb = xbf + (size_t)b * SEQ_L * D_MODEL;
    int l0 = seg * (SEQ_L / NSEG);

    f4 a0 = {0.f,0.f,0.f,0.f}, a1 = a0, a2 = a0, a3 = a0;
    #pragma unroll
    for (int i = 0; i < 32; i += 4) {
        #pragma unroll
        for (int k = 0; k < 4; ++k) {
            int l = l0 + ph + (i + k) * 16;
            f4 v = xb[l * 32 + c4];
            if (k == 0) a0 += v; else if (k == 1) a1 += v; else if (k == 2) a2 += v; else a3 += v;
            ushort4 o;
            o.x = f2bf(v[0]); o.y = f2bf(v[1]); o.z = f2bf(v[2]); o.w = f2bf(v[3]);
            reinterpret_cast<ushort4*>(xbb + (size_t)l * D_MODEL)[c4] = o;
        }
    }
    f4 acc = (a0 + a1) + (a2 + a3);

    __shared__ f4 red[512];
    red[t] = acc;
    __syncthreads();
    if (t < 32) {
        f4 s = red[t];
        #pragma unroll
        for (int p = 1; p < 16; ++p) s += red[t + 32 * p];
        reinterpret_cast<f4*>(part + ((size_t)b * NSEG + seg) * D_MODEL)[t] = s;
    }
}

// load 6 consecutive bf16 token-rows (8 channels each) around this thread's 4 rows
template<bool GUARD>
__device__ __forceinline__ void load6b(const unsigned short* __restrict__ xbb,
                                       int gr0, int c8, u32x4 R[6]) {
    #pragma unroll
    for (int j = 0; j < 6; ++j) {
        int gr = gr0 + j;
        if (GUARD) {
            bool ok = (gr >= 0) && (gr < SEQ_L);
            int grc = ok ? gr : 0;
            u32x4 v = reinterpret_cast<const u32x4*>(xbb + (size_t)grc * D_MODEL)[c8];
            u32x4 z = {0u, 0u, 0u, 0u};
            R[j] = ok ? v : z;
        } else {
            R[j] = reinterpret_cast<const u32x4*>(xbb + (size_t)gr * D_MODEL)[c8];
        }
    }
}

// kernel 3A body: block = 256 tokens = 2 tiles of 128, double-buffered swizzled LDS,
// 1 barrier per tile; tile1 loads issued before tile0's barrier (fly under MFMA).
template<bool GUARD>
__device__ __forceinline__ void kconv_body(const unsigned short* __restrict__ xbf,
                                           const float* __restrict__ wv,
                                           const unsigned short* __restrict__ wcb,
                                           const float* __restrict__ bc,
                                           float* __restrict__ out,
                                           unsigned short (*y_lds)[128][128]) {
    int t = threadIdx.x, b = blockIdx.y;
    int base = blockIdx.x * 256;
    const unsigned short* xbb = xbf + (size_t)b * SEQ_L * D_MODEL;
    float* outb = out + (size_t)b * SEQ_L * D_MODEL;

    int c8 = t & 15, rg = t >> 4;            // rg 0..31, owns rows rg*4..rg*4+3 of tile
    int lane = t & 63, wid = t >> 6;
    int r = lane & 15, q = lane >> 4, kb = q * 8;
    int co0 = wid * 16;

    // conv taps for this thread's 8-channel slice
    f4 w0a = *reinterpret_cast<const f4*>(wv + c8 * 8);
    f4 w0b = *reinterpret_cast<const f4*>(wv + c8 * 8 + 4);
    f4 w1a = *reinterpret_cast<const f4*>(wv + 128 + c8 * 8);
    f4 w1b = *reinterpret_cast<const f4*>(wv + 128 + c8 * 8 + 4);
    f4 w2a = *reinterpret_cast<const f4*>(wv + 256 + c8 * 8);
    f4 w2b = *reinterpret_cast<const f4*>(wv + 256 + c8 * 8 + 4);

    // Wc A-fragments (wave's 16-co block), loaded once
    bf16x8 awc[4];
    #pragma unroll
    for (int kc = 0; kc < 4; ++kc)
        awc[kc] = *reinterpret_cast<const bf16x8*>(wcb + (size_t)(co0 + r) * D_MODEL + kc * 32 + kb);

    f4 bcv = *reinterpret_cast<const f4*>(bc + co0 + q * 4);

    u32x4 R[6];
    load6b<GUARD>(xbb, base + rg * 4 - 1, c8, R);

    #pragma unroll
    for (int i = 0; i < 2; ++i) {
        // ---- stage: conv in f32, pack bf16, swizzled LDS write ----
        f4 pa, pb, ca, cb;
        unpk(R[0], pa, pb);
        unpk(R[1], ca, cb);
        #pragma unroll
        for (int j = 0; j < 4; ++j) {
            f4 na, nb;
            unpk(R[j + 2], na, nb);
            f4 y0 = pa * w0a + ca * w1a + na * w2a;
            f4 y1 = pb * w0b + cb * w1b + nb * w2b;
            u32x4 P;
            P.x = pack2bf(y0[0], y0[1]);
            P.y = pack2bf(y0[2], y0[3]);
            P.z = pack2bf(y1[0], y1[1]);
            P.w = pack2bf(y1[2], y1[3]);
            int row = rg * 4 + j;
            *reinterpret_cast<u32x4*>(&y_lds[i][row][(c8 ^ (row & 15)) * 8]) = P;
            pa = ca; pb = cb; ca = na; cb = nb;
        }
        // issue next tile's loads (in flight under MFMA+stores)
        if (i == 0) load6b<GUARD>(xbb, base + 128 + rg * 4 - 1, c8, R);
        __syncthreads();   // y_lds[i] visible

        // ---- MFMA: wave = 128 tokens x 16 co ----
        f32x4 acc[8];
        #pragma unroll
        for (int g = 0; g < 8; ++g) acc[g] = (f32x4){0.f, 0.f, 0.f, 0.f};
        #pragma unroll
        for (int g = 0; g < 8; ++g)
            #pragma unroll
            for (int kc = 0; kc < 4; ++kc) {
                bf16x8 bv = *reinterpret_cast<const bf16x8*>(
                    &y_lds[i][g * 16 + r][((kc * 4 + q) ^ r) * 8]);
                acc[g] = __builtin_amdgcn_mfma_f32_16x16x32_bf16(awc[kc], bv, acc[g], 0, 0, 0);
            }

        // ---- epilogue: token = base+i*128+g*16+r, co = co0+q*4+reg ----
        #pragma unroll
        for (int g = 0; g < 8; ++g) {
            int tok = base + i * 128 + g * 16 + r;
            *reinterpret_cast<f4*>(outb + (size_t)tok * D_MODEL + co0 + q * 4) = acc[g] + bcv;
        }
        // no trailing barrier: tile1 uses the other buffer
    }
}

// grid (SEQ_L/256, BATCH), 512 threads = 8 waves; wave w -> co block w*16.
__global__ __launch_bounds__(512, 4) void kconv_a(const unsigned short* __restrict__ xbf,
                                                  const float* __restrict__ wv,
                                                  const unsigned short* __restrict__ wcb,
                                                  const float* __restrict__ bc,
                                                  float* __restrict__ out) {
    __shared__ __align__(16) unsigned short y_lds[2][128][128];   // 64 KB, XOR-swizzled
    if (blockIdx.x == 0 || blockIdx.x == gridDim.x - 1)
        kconv_body<true>(xbf, wv, wcb, bc, out, y_lds);
    else
        kconv_body<false>(xbf, wv, wcb, bc, out, y_lds);
}

// ============================ PATH B (fallback = round-6 proven) ============================

__global__ __launch_bounds__(512) void kmean_b(const float* __restrict__ x,
                                               float* __restrict__ part,
                                               const float* __restrict__ Wc,
                                               unsigned short* __restrict__ wcb) {
    if (blockIdx.x == NSEG) {
        if (blockIdx.y < 8) {
            int i = blockIdx.y * 512 + threadIdx.x;
            f4 v = reinterpret_cast<const f4*>(Wc)[i];
            ushort4 o;
            o.x = f2bf(v[0]); o.y = f2bf(v[1]); o.z = f2bf(v[2]); o.w = f2bf(v[3]);
            reinterpret_cast<ushort4*>(wcb)[i] = o;
        }
        return;
    }
    int seg = blockIdx.x, b = blockIdx.y;
    int t = threadIdx.x;
    int c4 = t & 31, ph = t >> 5;
    const f4* xb = reinterpret_cast<const f4*>(x + (size_t)b * SEQ_L * D_MODEL);
    int l0 = seg * (SEQ_L / NSEG);

    f4 a0 = {0.f,0.f,0.f,0.f}, a1 = a0, a2 = a0, a3 = a0;
    #pragma unroll
    for (int i = 0; i < 32; i += 4) {
        a0 += xb[(l0 + ph + (i + 0) * 16) * 32 + c4];
        a1 += xb[(l0 + ph + (i + 1) * 16) * 32 + c4];
        a2 += xb[(l0 + ph + (i + 2) * 16) * 32 + c4];
        a3 += xb[(l0 + ph + (i + 3) * 16) * 32 + c4];
    }
    f4 acc = (a0 + a1) + (a2 + a3);

    __shared__ f4 red[512];
    red[t] = acc;
    __syncthreads();
    if (t < 32) {
        f4 s = red[t];
        #pragma unroll
        for (int p = 1; p < 16; ++p) s += red[t + 32 * p];
        reinterpret_cast<f4*>(part + ((size_t)b * NSEG + seg) * D_MODEL)[t] = s;
    }
}

template<bool GUARD>
__device__ __forceinline__ void load6(const float* __restrict__ xb, int gr0, int c4, f4 R[6]) {
    #pragma unroll
    for (int j = 0; j < 6; ++j) {
        int gr = gr0 + j;
        if (GUARD) {
            bool ok = (gr >= 0) && (gr < SEQ_L);
            int grc = ok ? gr : 0;
            f4 v = reinterpret_cast<const f4*>(xb + (size_t)grc * D_MODEL)[c4];
            f4 z = {0.f, 0.f, 0.f, 0.f};
            R[j] = ok ? v : z;
        } else {
            R[j] = reinterpret_cast<const f4*>(xb + (size_t)gr * D_MODEL)[c4];
        }
    }
}

__global__ __launch_bounds__(512, 2) void kconv_b(const float* __restrict__ x,
                                                  const float* __restrict__ wv,
                                                  const unsigned short* __restrict__ wcb,
                                                  const float* __restrict__ bc,
                                                  float* __restrict__ out) {
    __shared__ __align__(16) unsigned short y_lds[2][64][132];

    int t = threadIdx.x;
    int b = blockIdx.y;
    int base = blockIdx.x * 256;
    const float* xb = x + (size_t)b * SEQ_L * D_MODEL;
    float* outb = out + (size_t)b * SEQ_L * D_MODEL;

    int c4 = t & 31, rg = t >> 5;
    int lane = t & 63, wid = t >> 6;
    int r = lane & 15, q = lane >> 4, kb = q * 8;
    int co0 = wid * 16;

    f4 w0 = reinterpret_cast<const f4*>(wv)[c4];
    f4 w1 = reinterpret_cast<const f4*>(wv + 128)[c4];
    f4 w2 = reinterpret_cast<const f4*>(wv + 256)[c4];

    bf16x8 awc[4];
    #pragma unroll
    for (int kc = 0; kc < 4; ++kc)
        awc[kc] = *reinterpret_cast<const bf16x8*>(wcb + (size_t)(co0 + r) * D_MODEL + kc * 32 + kb);

    f4 bcv = *reinterpret_cast<const f4*>(bc + co0 + q * 4);

    f4 R[6];
    if (base == 0) load6<true>(xb, base + rg * 4 - 1, c4, R);
    else           load6<false>(xb, base + rg * 4 - 1, c4, R);

    #pragma unroll
    for (int i = 0; i < 4; ++i) {
        int buf = i & 1;
        #pragma unroll
        for (int j = 0; j < 4; ++j) {
            f4 y = R[j] * w0 + R[j + 1] * w1 + R[j + 2] * w2;
            ushort4 yb;
            yb.x = f2bf(y[0]); yb.y = f2bf(y[1]); yb.z = f2bf(y[2]); yb.w = f2bf(y[3]);
            *reinterpret_cast<ushort4*>(&y_lds[buf][rg * 4 + j][c4 * 4]) = yb;
        }
        if (i < 3) {
            int ntok0 = base + (i + 1) * 64;
            if (ntok0 + 64 == SEQ_L) load6<true>(xb, ntok0 + rg * 4 - 1, c4, R);
            else                     load6<false>(xb, ntok0 + rg * 4 - 1, c4, R);
        }
        __syncthreads();

        f32x4 acc[4];
        #pragma unroll
        for (int g = 0; g < 4; ++g) acc[g] = (f32x4){0.f, 0.f, 0.f, 0.f};
        #pragma unroll
        for (int g = 0; g < 4; ++g)
            #pragma unroll
            for (int kc = 0; kc < 4; ++kc) {
                bf16x8 bv = *reinterpret_cast<const bf16x8*>(&y_lds[buf][g * 16 + r][kc * 32 + kb]);
                acc[g] = __builtin_amdgcn_mfma_f32_16x16x32_bf16(awc[kc], bv, acc[g], 0, 0, 0);
            }

        int tokt = base + i * 64;
        #pragma unroll
        for (int g = 0; g < 4; ++g) {
            int tok = tokt + g * 16 + r;
            *reinterpret_cast<f4*>(outb + (size_t)tok * D_MODEL + co0 + q * 4) = acc[g] + bcv;
        }
        __syncthreads();
    }
}

// ---------------- kernel 2 (shared): per-channel MLP + softmax -> w[3][128] ----------------
__global__ __launch_bounds__(128) void kweights(const float* __restrict__ part,
                                                const float* __restrict__ W1,
                                                const float* __restrict__ b1,
                                                const float* __restrict__ W2,
                                                const float* __restrict__ b2,
                                                float* __restrict__ w) {
    int c = threadIdx.x; // 0..127
    f4 mv[32];
    #pragma unroll
    for (int d4 = 0; d4 < 32; ++d4) mv[d4] = (f4){0.f, 0.f, 0.f, 0.f};
    for (int s = 0; s < NSEG; ++s) {
        const f4* ps = reinterpret_cast<const f4*>(part + ((size_t)c * NSEG + s) * D_MODEL);
        #pragma unroll
        for (int d4 = 0; d4 < 32; ++d4) mv[d4] += ps[d4];
    }
    #pragma unroll
    for (int d4 = 0; d4 < 32; ++d4) mv[d4] *= (1.0f / (float)SEQ_L);

    float h[32];
    #pragma unroll
    for (int j = 0; j < 32; ++j) {
        const f4* w1r = reinterpret_cast<const f4*>(W1 + j * 128);
        f4 s4 = {0.f, 0.f, 0.f, 0.f};
        #pragma unroll
        for (int d4 = 0; d4 < 32; ++d4) s4 += mv[d4] * w1r[d4];
        float s = s4[0] + s4[1] + s4[2] + s4[3] + b1[j];
        h[j] = 0.5f * s * (1.0f + erff(s * 0.70710678118654752f)); // exact gelu
    }
    float lg[3];
    float mx = -1e30f;
    #pragma unroll
    for (int k = 0; k < 3; ++k) {
        float s = b2[k];
        #pragma unroll
        for (int j = 0; j < 32; ++j) s += h[j] * W2[k * 32 + j];
        lg[k] = s;
        mx = fmaxf(mx, s);
    }
    float e[3], den = 0.f;
    #pragma unroll
    for (int k = 0; k < 3; ++k) { e[k] = __expf(lg[k] - mx); den += e[k]; }
    float inv = 1.0f / den;
    #pragma unroll
    for (int k = 0; k < 3; ++k) w[k * 128 + c] = e[k] * inv;
}

extern "C" void kernel_launch(void* const* d_in, const int* in_sizes, int n_in,
                              void* d_out, int out_size, void* d_ws, size_t ws_size,
                              hipStream_t stream) {
    const float* x  = (const float*)d_in[0];
    const float* W1 = (const float*)d_in[1];
    const float* b1 = (const float*)d_in[2];
    const float* W2 = (const float*)d_in[3];
    const float* b2 = (const float*)d_in[4];
    const float* Wc = (const float*)d_in[5];
    const float* bc = (const float*)d_in[6];
    float* out = (float*)d_out;

    char* ws = (char*)d_ws;
    const size_t XBF_BYTES = (size_t)BATCH * SEQ_L * D_MODEL * 2;   // 128 MB
    const size_t NEED = XBF_BYTES + 524288 + 4096 + 32768;

    if (ws_size >= NEED) {
        unsigned short* xbf = (unsigned short*)ws;
        float* part = (float*)(ws + XBF_BYTES);
        float* w    = (float*)(ws + XBF_BYTES + 524288);
        unsigned short* wcb = (unsigned short*)(ws + XBF_BYTES + 524288 + 4096);

        kmean_a<<<dim3(NSEG + 1, BATCH), 512, 0, stream>>>(x, part, Wc, wcb, xbf);
        kweights<<<1, 128, 0, stream>>>(part, W1, b1, W2, b2, w);
        kconv_a<<<dim3(SEQ_L / 256, BATCH), 512, 0, stream>>>(xbf, w, wcb, bc, out);
    } else {
        float* part = (float*)ws;                               // 512 KB
        float* w    = (float*)(ws + 524288);                    // 1.5 KB
        unsigned short* wcb = (unsigned short*)(ws + 526336);   // 32 KB

        kmean_b<<<dim3(NSEG + 1, BATCH), 512, 0, stream>>>(x, part, Wc, wcb);
        kweights<<<1, 128, 0, stream>>>(part, W1, b1, W2, b2, w);
        kconv_b<<<dim3(SEQ_L / 256, BATCH), 512, 0, stream>>>(x, w, wcb, bc, out);
    }
}

// Round 8
// 244.291 us; speedup vs baseline: 1.0993x; 1.0993x over previous
//
#include <hip/hip_runtime.h>
#include <hip/hip_bf16.h>

#define D_MODEL 128
#define SEQ_L   4096
#define BATCH   128
#define NSEG    16    // kmean segments (256 tokens each)

typedef float f4 __attribute__((ext_vector_type(4)));
typedef float f32x4 __attribute__((ext_vector_type(4)));
typedef short bf16x8 __attribute__((ext_vector_type(8)));

__device__ __forceinline__ unsigned short f2bf(float f) {
    union { float f; unsigned u; } v; v.f = f;
    unsigned r = v.u + 0x7FFFu + ((v.u >> 16) & 1u);
    return (unsigned short)(r >> 16);
}

// ---------------- kernel 1: partial mean over L (+ folded Wc->bf16 cvt) ----------------
// grid (NSEG+1, 128), 512 threads. 16 INDEPENDENT loads -> tree sum (latency fix).
__global__ __launch_bounds__(512) void kmean(const float* __restrict__ x,
                                             float* __restrict__ part,
                                             const float* __restrict__ Wc,
                                             unsigned short* __restrict__ wcb) {
    if (blockIdx.x == NSEG) {
        if (blockIdx.y < 8) {
            int i = blockIdx.y * 512 + threadIdx.x;   // 4096 threads x 4 floats = 16384
            f4 v = reinterpret_cast<const f4*>(Wc)[i];
            ushort4 o;
            o.x = f2bf(v[0]); o.y = f2bf(v[1]); o.z = f2bf(v[2]); o.w = f2bf(v[3]);
            reinterpret_cast<ushort4*>(wcb)[i] = o;
        }
        return;
    }
    int seg = blockIdx.x, b = blockIdx.y;
    int t = threadIdx.x;
    int c4 = t & 31, ph = t >> 5;                 // ph: 0..15
    const f4* xb = reinterpret_cast<const f4*>(x + (size_t)b * SEQ_L * D_MODEL);
    int l0 = seg * (SEQ_L / NSEG);                // 256 tokens per block

    // 16 independent 16B loads, all in flight before any use
    f4 R[16];
    #pragma unroll
    for (int j = 0; j < 16; ++j)
        R[j] = xb[(l0 + ph + j * 16) * 32 + c4];

    // tree sum
    #pragma unroll
    for (int s = 8; s >= 1; s >>= 1)
        #pragma unroll
        for (int j = 0; j < s; ++j) R[j] += R[j + s];

    __shared__ f4 red[512];
    red[t] = R[0];
    __syncthreads();
    if (t < 32) {
        f4 s = red[t];
        #pragma unroll
        for (int p = 1; p < 16; ++p) s += red[t + 32 * p];
        reinterpret_cast<f4*>(part + ((size_t)b * NSEG + seg) * D_MODEL)[t] = s;
    }
}

// ---------------- kernel 2: per-channel MLP + softmax -> w[3][128] ----------------
__global__ __launch_bounds__(128) void kweights(const float* __restrict__ part,
                                                const float* __restrict__ W1,
                                                const float* __restrict__ b1,
                                                const float* __restrict__ W2,
                                                const float* __restrict__ b2,
                                                float* __restrict__ w) {
    int c = threadIdx.x; // 0..127
    f4 mv[32];
    #pragma unroll
    for (int d4 = 0; d4 < 32; ++d4) mv[d4] = (f4){0.f, 0.f, 0.f, 0.f};
    for (int s = 0; s < NSEG; ++s) {
        const f4* ps = reinterpret_cast<const f4*>(part + ((size_t)c * NSEG + s) * D_MODEL);
        #pragma unroll
        for (int d4 = 0; d4 < 32; ++d4) mv[d4] += ps[d4];
    }
    #pragma unroll
    for (int d4 = 0; d4 < 32; ++d4) mv[d4] *= (1.0f / (float)SEQ_L);

    float h[32];
    #pragma unroll
    for (int j = 0; j < 32; ++j) {
        const f4* w1r = reinterpret_cast<const f4*>(W1 + j * 128);
        f4 s4 = {0.f, 0.f, 0.f, 0.f};
        #pragma unroll
        for (int d4 = 0; d4 < 32; ++d4) s4 += mv[d4] * w1r[d4];
        float s = s4[0] + s4[1] + s4[2] + s4[3] + b1[j];
        h[j] = 0.5f * s * (1.0f + erff(s * 0.70710678118654752f)); // exact gelu
    }
    float lg[3];
    float mx = -1e30f;
    #pragma unroll
    for (int k = 0; k < 3; ++k) {
        float s = b2[k];
        #pragma unroll
        for (int j = 0; j < 32; ++j) s += h[j] * W2[k * 32 + j];
        lg[k] = s;
        mx = fmaxf(mx, s);
    }
    float e[3], den = 0.f;
    #pragma unroll
    for (int k = 0; k < 3; ++k) { e[k] = __expf(lg[k] - mx); den += e[k]; }
    float inv = 1.0f / den;
    #pragma unroll
    for (int k = 0; k < 3; ++k) w[k * 128 + c] = e[k] * inv;
}

// ---------------- kernel 3: fused conv + matmul, pipelined LDS double-buffer ----------------
template<bool GUARD>
__device__ __forceinline__ void load6(const float* __restrict__ xb, int gr0, int c4, f4 R[6]) {
    #pragma unroll
    for (int j = 0; j < 6; ++j) {
        int gr = gr0 + j;
        if (GUARD) {
            bool ok = (gr >= 0) && (gr < SEQ_L);
            int grc = ok ? gr : 0;
            f4 v = reinterpret_cast<const f4*>(xb + (size_t)grc * D_MODEL)[c4];
            f4 z = {0.f, 0.f, 0.f, 0.f};
            R[j] = ok ? v : z;
        } else {
            R[j] = reinterpret_cast<const f4*>(xb + (size_t)gr * D_MODEL)[c4];
        }
    }
}

// grid (SEQ_L/256, BATCH), 512 threads = 8 waves; wave w -> co block w*16.
// Per 64-token half-tile: issue next loads FIRST (dual R sets), conv->LDS,
// ONE barrier, MFMA, NT stores. Trailing barrier removed (double buffer is safe:
// the pre-MFMA barrier of iter i+1 proves all waves passed MFMA(i) before buf reuse at i+2).
__global__ __launch_bounds__(512, 2) void kconv(const float* __restrict__ x,
                                                const float* __restrict__ wv,
                                                const unsigned short* __restrict__ wcb,
                                                const float* __restrict__ bc,
                                                float* __restrict__ out) {
    __shared__ __align__(16) unsigned short y_lds[2][64][132];

    int t = threadIdx.x;
    int b = blockIdx.y;
    int base = blockIdx.x * 256;
    const float* xb = x + (size_t)b * SEQ_L * D_MODEL;
    float* outb = out + (size_t)b * SEQ_L * D_MODEL;

    int c4 = t & 31, rg = t >> 5;            // rg: 0..15, owns rows rg*4..rg*4+3 of half
    int lane = t & 63, wid = t >> 6;
    int r = lane & 15, q = lane >> 4, kb = q * 8;
    int co0 = wid * 16;

    // conv taps for this thread's channel quad
    f4 w0 = reinterpret_cast<const f4*>(wv)[c4];
    f4 w1 = reinterpret_cast<const f4*>(wv + 128)[c4];
    f4 w2 = reinterpret_cast<const f4*>(wv + 256)[c4];

    // Wc A-fragments, loaded once (L2-hot)
    bf16x8 awc[4];
    #pragma unroll
    for (int kc = 0; kc < 4; ++kc)
        awc[kc] = *reinterpret_cast<const bf16x8*>(wcb + (size_t)(co0 + r) * D_MODEL + kc * 32 + kb);

    f4 bcv = *reinterpret_cast<const f4*>(bc + co0 + q * 4);

    // dual register staging sets (ping-pong, statically indexed via full unroll)
    f4 R[2][6];
    if (base == 0) load6<true>(xb, base + rg * 4 - 1, c4, R[0]);
    else           load6<false>(xb, base + rg * 4 - 1, c4, R[0]);

    #pragma unroll
    for (int i = 0; i < 4; ++i) {
        const int cur = i & 1, nxt = cur ^ 1;
        // issue NEXT half's loads first — they fly under conv+barrier+MFMA+stores
        if (i < 3) {
            int ntok0 = base + (i + 1) * 64;
            if (ntok0 + 64 == SEQ_L) load6<true>(xb, ntok0 + rg * 4 - 1, c4, R[nxt]);
            else                     load6<false>(xb, ntok0 + rg * 4 - 1, c4, R[nxt]);
        }
        // conv (consumes R[cur]) + LDS write
        #pragma unroll
        for (int j = 0; j < 4; ++j) {
            f4 y = R[cur][j] * w0 + R[cur][j + 1] * w1 + R[cur][j + 2] * w2;
            ushort4 yb;
            yb.x = f2bf(y[0]); yb.y = f2bf(y[1]); yb.z = f2bf(y[2]); yb.w = f2bf(y[3]);
            *reinterpret_cast<ushort4*>(&y_lds[cur][rg * 4 + j][c4 * 4]) = yb;
        }
        __syncthreads();   // y_lds[cur] visible

        // MFMA: wave = 64 tokens x 16 co
        f32x4 acc[4];
        #pragma unroll
        for (int g = 0; g < 4; ++g) acc[g] = (f32x4){0.f, 0.f, 0.f, 0.f};
        #pragma unroll
        for (int g = 0; g < 4; ++g)
            #pragma unroll
            for (int kc = 0; kc < 4; ++kc) {
                bf16x8 bv = *reinterpret_cast<const bf16x8*>(&y_lds[cur][g * 16 + r][kc * 32 + kb]);
                acc[g] = __builtin_amdgcn_mfma_f32_16x16x32_bf16(awc[kc], bv, acc[g], 0, 0, 0);
            }

        // epilogue: nontemporal stores (out never re-read; keep x resident in L2/L3)
        int tokt = base + i * 64;
        #pragma unroll
        for (int g = 0; g < 4; ++g) {
            int tok = tokt + g * 16 + r;
            f4 v = acc[g] + bcv;
            __builtin_nontemporal_store(v, reinterpret_cast<f4*>(outb + (size_t)tok * D_MODEL + co0 + q * 4));
        }
        // no trailing barrier (double-buffered)
    }
}

extern "C" void kernel_launch(void* const* d_in, const int* in_sizes, int n_in,
                              void* d_out, int out_size, void* d_ws, size_t ws_size,
                              hipStream_t stream) {
    const float* x  = (const float*)d_in[0];
    const float* W1 = (const float*)d_in[1];
    const float* b1 = (const float*)d_in[2];
    const float* W2 = (const float*)d_in[3];
    const float* b2 = (const float*)d_in[4];
    const float* Wc = (const float*)d_in[5];
    const float* bc = (const float*)d_in[6];
    float* out = (float*)d_out;

    char* ws = (char*)d_ws;
    float* part = (float*)ws;                                 // 128*16*128*4 = 1 MB
    float* w    = (float*)(ws + 1048576);                     // 1.5 KB
    unsigned short* wcb = (unsigned short*)(ws + 1052672);    // 32 KB

    kmean<<<dim3(NSEG + 1, BATCH), 512, 0, stream>>>(x, part, Wc, wcb);
    kweights<<<1, 128, 0, stream>>>(part, W1, b1, W2, b2, w);
    kconv<<<dim3(SEQ_L / 256, BATCH), 512, 0, stream>>>(x, w, wcb, bc, out);
}